// Round 5
// baseline (201.241 us; speedup 1.0000x reference)
//
#include <hip/hip_runtime.h>
#include <stdint.h>

#define N_  32
#define C_  128
#define H_  56
#define W_  56
#define HW_ 3136
#define P_  128

using i32x4 = __attribute__((ext_vector_type(4))) int;

// ws layout (bytes):
//   wI8 : P*1152 = 147,456  (i8 +1/-1 weights, [p][tap*128+c])
//   inv : P*4
//   b0  : P*4
#define WI8_BYTES (P_*1152)

// ------- pack weights to i8 +1/-1 in [p][t*128+c] layout; fold BN ------------
__global__ __launch_bounds__(256) void wpack_kernel(const float* __restrict__ weight,
        const float* __restrict__ bias, const float* __restrict__ gamma,
        const float* __restrict__ beta, const float* __restrict__ mean,
        const float* __restrict__ var,
        uint32_t* __restrict__ wI8, float* __restrict__ invG, float* __restrict__ b0G) {
    int gid = blockIdx.x * 256 + threadIdx.x;        // 144 blocks = 36864 dwords
    int p   = gid / 288;
    int rem = gid % 288;
    int k   = rem * 4;                               // k = t*128 + c
    int tp  = k >> 7;
    int c   = k & 127;
    uint32_t d = 0;
    #pragma unroll
    for (int i2 = 0; i2 < 4; ++i2) {
        float v = weight[((size_t)p * C_ + c + i2) * 9 + tp];
        uint32_t by = (v >= 0.f) ? 0x01u : 0xFFu;
        d |= by << (8 * i2);
    }
    wI8[gid] = d;
    if (blockIdx.x == 0 && threadIdx.x < P_) {
        int pp = threadIdx.x;
        float inv = gamma[pp] * rsqrtf(var[pp] + 1e-5f);
        invG[pp] = inv;
        b0G[pp]  = bias[pp] * inv + beta[pp] - mean[pp] * inv;
    }
}

// ------- fused: sign-binarize x in-kernel + binary conv via i8 MFMA + BN + res
// R5: two row-pair tiles per block over a 6-row LDS ring (rows r0b-1..r0b+4).
// Why: R2 (60us) was latency-bound with non-overlapped phases + a 128-block
// tail round; R1/R3/R4 proved forcing 4 blocks/CU via launch_bounds(256,4)
// always spills (allocator splits 128 as 64 arch + 64 acc). With grid=448 and
// >=2 blocks/CU guaranteed (LDS 53KB -> 3/CU; regs uncapped), the WHOLE grid
// is resident in one round: register pressure becomes non-binding.
// Gains: expansion loads -25% (6 rows vs 8 for the same outputs), no tail
// round, tile-1's 2-row expansion overlaps tile-0's epilogue.
// Main loop / swizzle / double-buffered weights identical to the verified R2.
__global__ __launch_bounds__(256) void bconv_kernel(
        const uint4* __restrict__ wI8v,
        const float* __restrict__ invG, const float* __restrict__ b0G,
        const float* __restrict__ x, float* __restrict__ out) {
    __shared__ uint4 actT[6 * 68 * 8];   // 52,224 B ring: [slot][colL][chunk^swz]
    __shared__ float sInv[P_], sB0[P_];

    int tid = threadIdx.x;
    int img = blockIdx.x / 14;           // 14 blocks per image (4 rows each)
    int r0b = (blockIdx.x % 14) * 4;     // block's first output row

    int lane = tid & 63;
    int wi   = tid >> 6;
    int q    = lane >> 4;
    int l15  = lane & 15;
    int m0   = wi * 32;

    if (tid < P_) { sInv[tid] = invG[tid]; sB0[tid] = b0G[tid]; }

    // expand one (slot, input-row h, 32-ch group cg, 4-col group tq) unit:
    // 32 x uint4 loads (4 pixels x 32 channels) -> 8 swizzled uint4 LDS stores
    auto expandCell = [&](int slot, int h, int cg, int tq) {
        bool vh = ((unsigned)h < (unsigned)H_);
        uint32_t c0 = vh ? 0x01010101u : 0u;   // invalid row -> all-zero bytes
        uint32_t cf = vh ? 0xFEu       : 0u;
        const uint32_t* xb = (const uint32_t*)x
            + ((size_t)img * C_ + cg * 32) * HW_ + (vh ? h : 0) * W_ + tq * 4;
        int colL0 = tq * 4 + 1;                // cells colL 1..56 (wv 0..55)
        #pragma unroll
        for (int ph = 0; ph < 2; ++ph) {       // 16 channels per pass
            uint32_t cell0[4], cell1[4], cell2[4], cell3[4];
            #pragma unroll
            for (int d = 0; d < 4; ++d) {      // dword d = channels d*4..d*4+3
                uint32_t w0 = 0, w1 = 0, w2 = 0, w3 = 0;
                if (vh) {
                    #pragma unroll
                    for (int i = 0; i < 4; ++i) {
                        uint4 u = *(const uint4*)(xb + (size_t)(ph * 16 + d * 4 + i) * HW_);
                        uint32_t sh = i * 8;
                        w0 |= (u.x >> 31) << sh;
                        w1 |= (u.y >> 31) << sh;
                        w2 |= (u.z >> 31) << sh;
                        w3 |= (u.w >> 31) << sh;
                    }
                }
                cell0[d] = c0 + w0 * cf;
                cell1[d] = c0 + w1 * cf;
                cell2[d] = c0 + w2 * cf;
                cell3[d] = c0 + w3 * cf;
            }
            int cb = cg * 2 + ph;              // 16-channel chunk index
            actT[(slot * 68 + colL0 + 0) * 8 + (cb ^ ((colL0 + 0) & 7))] =
                make_uint4(cell0[0], cell0[1], cell0[2], cell0[3]);
            actT[(slot * 68 + colL0 + 1) * 8 + (cb ^ ((colL0 + 1) & 7))] =
                make_uint4(cell1[0], cell1[1], cell1[2], cell1[3]);
            actT[(slot * 68 + colL0 + 2) * 8 + (cb ^ ((colL0 + 2) & 7))] =
                make_uint4(cell2[0], cell2[1], cell2[2], cell2[3]);
            actT[(slot * 68 + colL0 + 3) * 8 + (cb ^ ((colL0 + 3) & 7))] =
                make_uint4(cell3[0], cell3[1], cell3[2], cell3[3]);
        }
    };

    // ---- phase 1: expand rows r0b-1 .. r0b+2 into slots 0..3 ----
    if (tid < 224) {
        int rho = tid / 56;
        int rr  = tid % 56;
        expandCell(rho, r0b - 1 + rho, rr / 14, rr % 14);
    } else {
        // 32 threads zero halo cells (colL==0 and 57..67) for slots 0..3
        int z = tid - 224;
        #pragma unroll
        for (int rep = 0; rep < 2; ++rep) {
            int e = z + rep * 32;
            if (e < 48) {
                int rho  = e / 12;
                int jj   = e % 12;
                int colL = jj ? (56 + jj) : 0;
                int base = (rho * 68 + colL) * 8;
                #pragma unroll
                for (int s = 0; s < 8; ++s) actT[base + s] = make_uint4(0u,0u,0u,0u);
            }
        }
    }

    __syncthreads();                     // barrier 1: slots 0..3 ready

    #pragma unroll 1
    for (int tt = 0; tt < 2; ++tt) {     // two row-pair tiles, shared ring
        int rho_off = tt * 2;            // tile reads slots rho_off..rho_off+3

        // tap-0 weight prefetch (L2-hot), double-buffered across taps
        i32x4 aw[2][2][2];               // [buf][mi][ks]
        #pragma unroll
        for (int mi = 0; mi < 2; ++mi)
            #pragma unroll
            for (int ks = 0; ks < 2; ++ks)
                aw[0][mi][ks] = *(const i32x4*)&wI8v[(size_t)(m0 + mi*16 + l15) * 72
                                                     + ks * 4 + q];

        i32x4 acc[2][8];
        #pragma unroll
        for (int mi = 0; mi < 2; ++mi)
            #pragma unroll
            for (int j = 0; j < 8; ++j)
                #pragma unroll
                for (int e = 0; e < 4; ++e) acc[mi][j][e] = 0;

        for (int t9 = 0; t9 < 9; ++t9) {
            int nb = t9 & 1;
            if (t9 < 8) {                // prefetch next tap's weights
                #pragma unroll
                for (int mi = 0; mi < 2; ++mi)
                    #pragma unroll
                    for (int ks = 0; ks < 2; ++ks)
                        aw[nb ^ 1][mi][ks] = *(const i32x4*)&wI8v[(size_t)(m0 + mi*16 + l15) * 72
                                                                  + (t9 + 1) * 8 + ks * 4 + q];
            }
            int dh = t9 / 3, dw = t9 % 3;
            #pragma unroll
            for (int ks = 0; ks < 2; ++ks) {
                #pragma unroll
                for (int j = 0; j < 8; ++j) {
                    int n    = j * 16 + l15;
                    int colL = (n & 63) + dw;
                    int slot = (n >> 6) + dh + rho_off;
                    i32x4 bf = *(const i32x4*)&actT[(slot * 68 + colL) * 8
                                                    + ((ks * 4 + q) ^ (colL & 7))];
                    acc[0][j] = __builtin_amdgcn_mfma_i32_16x16x64_i8(aw[nb][0][ks], bf, acc[0][j], 0, 0, 0);
                    acc[1][j] = __builtin_amdgcn_mfma_i32_16x16x64_i8(aw[nb][1][ks], bf, acc[1][j], 0, 0, 0);
                }
            }
        }

        if (tt == 0) {
            // ---- phase 2: expand rows r0b+3, r0b+4 into slots 4,5 ----
            // (overlaps tile-0 epilogue below; disjoint from slots 0..3 that
            //  other waves may still be reading)
            if (tid < 112) {
                int rho2 = tid / 56;
                int rr   = tid % 56;
                expandCell(4 + rho2, r0b + 3 + rho2, rr / 14, rr % 14);
            } else if (tid < 136) {
                int e    = tid - 112;    // 0..23: halo cells for slots 4,5
                int rho2 = e / 12;
                int jj   = e % 12;
                int colL = jj ? (56 + jj) : 0;
                int base = ((4 + rho2) * 68 + colL) * 8;
                #pragma unroll
                for (int s = 0; s < 8; ++s) actT[base + s] = make_uint4(0u,0u,0u,0u);
            }
        }

        // ---- epilogue: BN + residual, coalesced 64B segments ----
        #pragma unroll
        for (int j = 0; j < 8; ++j) {
            int n = j * 16 + l15;
            int w = n & 63;
            if (w < W_) {
                int orow = r0b + rho_off + (n >> 6);
                size_t pixOff = (size_t)img * P_ * HW_ + (size_t)orow * W_ + w;
                #pragma unroll
                for (int mi = 0; mi < 2; ++mi)
                    #pragma unroll
                    for (int reg = 0; reg < 4; ++reg) {
                        int m = m0 + mi * 16 + q * 4 + reg;
                        size_t off = pixOff + (size_t)m * HW_;
                        out[off] = (float)acc[mi][j][reg] * sInv[m] + sB0[m] + x[off];
                    }
            }
        }

        if (tt == 0) __syncthreads();    // barrier 2: slots 4,5 ready
    }
}

extern "C" void kernel_launch(void* const* d_in, const int* in_sizes, int n_in,
                              void* d_out, int out_size, void* d_ws, size_t ws_size,
                              hipStream_t stream) {
    const float* x      = (const float*)d_in[0];
    const float* weight = (const float*)d_in[1];
    const float* bias   = (const float*)d_in[2];
    const float* gamma  = (const float*)d_in[3];
    const float* beta   = (const float*)d_in[4];
    const float* mean   = (const float*)d_in[5];
    const float* var    = (const float*)d_in[6];
    float* out = (float*)d_out;

    uint8_t*  ws    = (uint8_t*)d_ws;
    uint32_t* wI8   = (uint32_t*)ws;
    float*    invG  = (float*)(ws + WI8_BYTES);
    float*    b0G   = invG + P_;

    wpack_kernel<<<144, 256, 0, stream>>>(weight, bias, gamma, beta, mean, var, wI8, invG, b0G);
    bconv_kernel<<<32 * 14, 256, 0, stream>>>((const uint4*)wI8, invG, b0G, x, out);
}

// Round 6
// 143.500 us; speedup vs baseline: 1.4024x; 1.4024x over previous
//
#include <hip/hip_runtime.h>
#include <stdint.h>

#define N_  32
#define C_  128
#define H_  56
#define W_  56
#define HW_ 3136
#define P_  128

using i32x4 = __attribute__((ext_vector_type(4))) int;

// ws layout (bytes):
//   wI8 : P*1152 = 147,456  (i8 +1/-1 weights, [p][tap*128+c])
//   inv : P*4
//   b0  : P*4
#define WI8_BYTES (P_*1152)

// ------- pack weights to i8 +1/-1 in [p][t*128+c] layout; fold BN ------------
__global__ __launch_bounds__(256) void wpack_kernel(const float* __restrict__ weight,
        const float* __restrict__ bias, const float* __restrict__ gamma,
        const float* __restrict__ beta, const float* __restrict__ mean,
        const float* __restrict__ var,
        uint32_t* __restrict__ wI8, float* __restrict__ invG, float* __restrict__ b0G) {
    int gid = blockIdx.x * 256 + threadIdx.x;        // 144 blocks = 36864 dwords
    int p   = gid / 288;
    int rem = gid % 288;
    int k   = rem * 4;                               // k = t*128 + c
    int tp  = k >> 7;
    int c   = k & 127;
    uint32_t d = 0;
    #pragma unroll
    for (int i2 = 0; i2 < 4; ++i2) {
        float v = weight[((size_t)p * C_ + c + i2) * 9 + tp];
        uint32_t by = (v >= 0.f) ? 0x01u : 0xFFu;
        d |= by << (8 * i2);
    }
    wI8[gid] = d;
    if (blockIdx.x == 0 && threadIdx.x < P_) {
        int pp = threadIdx.x;
        float inv = gamma[pp] * rsqrtf(var[pp] + 1e-5f);
        invG[pp] = inv;
        b0G[pp]  = bias[pp] * inv + beta[pp] - mean[pp] * inv;
    }
}

// ------- fused: sign-binarize x in-kernel + binary conv via i8 MFMA + BN + res
// Block: 2 output rows x 64 cols x 128 out-ch (the verified R2 structure).
// R6 occupancy fix WITHOUT launch_bounds coercion (R1/R3/R4 all spilled under
// a forced cap): shave natural VGPR from 136 -> <=128 so waves/SIMD goes
// floor(512/136)=3 -> floor(512/128)=4, i.e. 16 waves/CU, 4 blocks/CU
// (LDS 35840B allows exactly 4), grid 896 fits one 1024-block round.
// Cuts: weights SINGLE-buffered (-16 regs; per-tap L2 load latency overlaps
// the 16 ds_read_b128 of the same tap + 16-wave TLP), acc init after barrier,
// no epilogue inv/b0 register hoist, #pragma unroll 1 on the tap loop so the
// compiler can't rebuild the double buffer.
// Tripwire: WRITE_SIZE must stay ~52MB (spill shows as +100MB+).
__global__ __launch_bounds__(256) void bconv_kernel(
        const uint4* __restrict__ wI8v,
        const float* __restrict__ invG, const float* __restrict__ b0G,
        const float* __restrict__ x, float* __restrict__ out) {
    __shared__ uint4 actT[4 * 68 * 8];   // 34816 B: [rho][colL][cblk ^ (colL&7)]
    __shared__ float sInv[P_], sB0[P_];

    int tid = threadIdx.x;
    int img = blockIdx.x / 28;
    int rp  = blockIdx.x % 28;
    int r0  = rp * 2;

    int lane = tid & 63;
    int wi   = tid >> 6;
    int q    = lane >> 4;
    int l15  = lane & 15;
    int m0   = wi * 32;

    if (tid < P_) { sInv[tid] = invG[tid]; sB0[tid] = b0G[tid]; }

    // ---- expand x signs -> i8 tile (+1/-1, 0 outside image), swizzled ------
    // 224 workers: (rho 0..3) x (cg 0..3: 32-ch group) x (tq 0..13: 4 cols).
    // Two passes of 16 channels each; per pass, per dword d (4 channels),
    // accumulate sign bits into 4 per-cell scalars -> all indices static.
    if (tid < 224) {
        int rho = tid / 56;
        int rr  = tid % 56;
        int cg  = rr / 14;               // channel group: c = cg*32 + ci
        int tq  = rr % 14;               // wv0 = tq*4
        int h   = r0 - 1 + rho;
        bool vh = ((unsigned)h < (unsigned)H_);
        uint32_t c0 = vh ? 0x01010101u : 0u;   // invalid row -> all-zero bytes
        uint32_t cf = vh ? 0xFEu       : 0u;
        const uint32_t* xb = (const uint32_t*)x
            + ((size_t)img * C_ + cg * 32) * HW_ + (vh ? h : 0) * W_ + tq * 4;
        int colL0 = tq * 4 + 1;                // cells colL 1..56 (wv 0..55)
        #pragma unroll
        for (int ph = 0; ph < 2; ++ph) {       // 16 channels per pass
            uint32_t cell0[4], cell1[4], cell2[4], cell3[4];
            #pragma unroll
            for (int d = 0; d < 4; ++d) {      // dword d = channels d*4..d*4+3
                uint32_t w0 = 0, w1 = 0, w2 = 0, w3 = 0;
                if (vh) {
                    #pragma unroll
                    for (int i = 0; i < 4; ++i) {
                        uint4 u = *(const uint4*)(xb + (size_t)(ph * 16 + d * 4 + i) * HW_);
                        uint32_t sh = i * 8;
                        w0 |= (u.x >> 31) << sh;
                        w1 |= (u.y >> 31) << sh;
                        w2 |= (u.z >> 31) << sh;
                        w3 |= (u.w >> 31) << sh;
                    }
                }
                cell0[d] = c0 + w0 * cf;
                cell1[d] = c0 + w1 * cf;
                cell2[d] = c0 + w2 * cf;
                cell3[d] = c0 + w3 * cf;
            }
            int cb = cg * 2 + ph;              // 16B chunk index (16 channels)
            actT[(rho * 68 + colL0 + 0) * 8 + (cb ^ ((colL0 + 0) & 7))] =
                make_uint4(cell0[0], cell0[1], cell0[2], cell0[3]);
            actT[(rho * 68 + colL0 + 1) * 8 + (cb ^ ((colL0 + 1) & 7))] =
                make_uint4(cell1[0], cell1[1], cell1[2], cell1[3]);
            actT[(rho * 68 + colL0 + 2) * 8 + (cb ^ ((colL0 + 2) & 7))] =
                make_uint4(cell2[0], cell2[1], cell2[2], cell2[3]);
            actT[(rho * 68 + colL0 + 3) * 8 + (cb ^ ((colL0 + 3) & 7))] =
                make_uint4(cell3[0], cell3[1], cell3[2], cell3[3]);
        }
    } else {
        // 32 threads zero the halo cells: colL==0 and colL 57..67, all 4 rows
        int z = tid - 224;
        #pragma unroll
        for (int rep = 0; rep < 2; ++rep) {
            int e = z + rep * 32;
            if (e < 48) {
                int rho  = e / 12;
                int jj   = e % 12;
                int colL = jj ? (56 + jj) : 0;
                int base = (rho * 68 + colL) * 8;
                #pragma unroll
                for (int s = 0; s < 8; ++s) actT[base + s] = make_uint4(0u,0u,0u,0u);
            }
        }
    }

    __syncthreads();                     // the ONLY barrier

    i32x4 acc[2][8];                     // init AFTER barrier: expansion-phase
    #pragma unroll                       // register peak stays low
    for (int mi = 0; mi < 2; ++mi)
        #pragma unroll
        for (int j = 0; j < 8; ++j)
            #pragma unroll
            for (int e = 0; e < 4; ++e) acc[mi][j][e] = 0;

    #pragma unroll 1
    for (int t9 = 0; t9 < 9; ++t9) {
        // single-buffered per-tap weights (16 arch regs); L2-hot, their latency
        // overlaps this tap's 16 ds_read_b128 + is hidden by 16 waves/CU TLP
        i32x4 aw[2][2];                  // [mi][ks]
        #pragma unroll
        for (int mi = 0; mi < 2; ++mi)
            #pragma unroll
            for (int ks = 0; ks < 2; ++ks)
                aw[mi][ks] = *(const i32x4*)&wI8v[(size_t)(m0 + mi*16 + l15) * 72
                                                  + t9 * 8 + ks * 4 + q];
        int dh = t9 / 3, dw = t9 % 3;
        #pragma unroll
        for (int ks = 0; ks < 2; ++ks) {
            #pragma unroll
            for (int j = 0; j < 8; ++j) {
                int n    = j * 16 + l15;
                int colL = (n & 63) + dw;
                int rho  = (n >> 6) + dh;
                i32x4 bf = *(const i32x4*)&actT[(rho * 68 + colL) * 8 + ((ks * 4 + q) ^ (colL & 7))];
                acc[0][j] = __builtin_amdgcn_mfma_i32_16x16x64_i8(aw[0][ks], bf, acc[0][j], 0, 0, 0);
                acc[1][j] = __builtin_amdgcn_mfma_i32_16x16x64_i8(aw[1][ks], bf, acc[1][j], 0, 0, 0);
            }
        }
    }

    // ---- epilogue: BN + residual, coalesced 64B segments; scale/shift read
    // straight from LDS (no register hoist) ----
    #pragma unroll
    for (int j = 0; j < 8; ++j) {
        int n = j * 16 + l15;
        int w = n & 63;
        if (w < W_) {
            int orow = r0 + (n >> 6);
            size_t pixOff = (size_t)img * P_ * HW_ + (size_t)orow * W_ + w;
            #pragma unroll
            for (int mi = 0; mi < 2; ++mi)
                #pragma unroll
                for (int reg = 0; reg < 4; ++reg) {
                    int m = m0 + mi * 16 + q * 4 + reg;
                    size_t off = pixOff + (size_t)m * HW_;
                    out[off] = (float)acc[mi][j][reg] * sInv[m] + sB0[m] + x[off];
                }
        }
    }
}

extern "C" void kernel_launch(void* const* d_in, const int* in_sizes, int n_in,
                              void* d_out, int out_size, void* d_ws, size_t ws_size,
                              hipStream_t stream) {
    const float* x      = (const float*)d_in[0];
    const float* weight = (const float*)d_in[1];
    const float* bias   = (const float*)d_in[2];
    const float* gamma  = (const float*)d_in[3];
    const float* beta   = (const float*)d_in[4];
    const float* mean   = (const float*)d_in[5];
    const float* var    = (const float*)d_in[6];
    float* out = (float*)d_out;

    uint8_t*  ws    = (uint8_t*)d_ws;
    uint32_t* wI8   = (uint32_t*)ws;
    float*    invG  = (float*)(ws + WI8_BYTES);
    float*    b0G   = invG + P_;

    wpack_kernel<<<144, 256, 0, stream>>>(weight, bias, gamma, beta, mean, var, wI8, invG, b0G);
    bconv_kernel<<<32 * 28, 256, 0, stream>>>((const uint4*)wI8, invG, b0G, x, out);
}